// Round 1
// baseline (429.213 us; speedup 1.0000x reference)
//
#include <hip/hip_runtime.h>

// DWT2 Haar: x (16,64,256,256) fp32 -> out (16,256,128,128) fp32
// out[n][band*64+ch][i][j] where band in {LL, H-row, H-col, HH}:
//   v0=x[2i,2j] v1=x[2i,2j+1] v2=x[2i+1,2j] v3=x[2i+1,2j+1]
//   out0=.5(v0+v1+v2+v3) out1=.5(v0+v1-v2-v3) out2=.5(v0-v1+v2-v3) out3=.5(v0-v1-v2+v3)
// Memory-bound: 1 GiB in + 1 GiB out -> ~340 us floor at 6.3 TB/s.

__global__ __launch_bounds__(256) void DWT2_kernel(const float* __restrict__ x,
                                                   float* __restrict__ out) {
    constexpr int C = 64, H2 = 128, W2 = 128, W = 256;
    // One thread = 2 output columns (one float4 load per input row).
    int idx = blockIdx.x * 256 + threadIdx.x;
    int jq = idx & 63;          // j/2 in [0,64)
    int t  = idx >> 6;
    int i  = t & 127;           // output row
    t >>= 7;
    int ch = t & 63;
    int nn = t >> 6;

    const float* p = x + (((size_t)(nn * C + ch) * 256 + 2 * i) * W + 4 * jq);
    float4 r0 = *(const float4*)p;          // row 2i   : cols 4jq..4jq+3
    float4 r1 = *(const float4*)(p + W);    // row 2i+1

    float2 o0, o1, o2, o3;
    {
        float s0 = r0.x + r0.y, d0 = r0.x - r0.y;
        float s1 = r1.x + r1.y, d1 = r1.x - r1.y;
        o0.x = 0.5f * (s0 + s1);
        o1.x = 0.5f * (s0 - s1);
        o2.x = 0.5f * (d0 + d1);
        o3.x = 0.5f * (d0 - d1);
        s0 = r0.z + r0.w; d0 = r0.z - r0.w;
        s1 = r1.z + r1.w; d1 = r1.z - r1.w;
        o0.y = 0.5f * (s0 + s1);
        o1.y = 0.5f * (s0 - s1);
        o2.y = 0.5f * (d0 + d1);
        o3.y = 0.5f * (d0 - d1);
    }

    size_t ob = (((size_t)nn * 4 * C + ch) * H2 + i) * W2 + 2 * jq;
    constexpr size_t band = (size_t)C * H2 * W2;  // 1 Mi elements = 4 MiB
    *(float2*)(out + ob)            = o0;
    *(float2*)(out + ob +     band) = o1;
    *(float2*)(out + ob + 2 * band) = o2;
    *(float2*)(out + ob + 3 * band) = o3;
}

extern "C" void kernel_launch(void* const* d_in, const int* in_sizes, int n_in,
                              void* d_out, int out_size, void* d_ws, size_t ws_size,
                              hipStream_t stream) {
    const float* x = (const float*)d_in[0];
    float* out = (float*)d_out;
    // total threads = 16*64*128*64 = 8,388,608 -> 32768 blocks of 256
    DWT2_kernel<<<32768, 256, 0, stream>>>(x, out);
}